// Round 4
// baseline (257.573 us; speedup 1.0000x reference)
//
#include <hip/hip_runtime.h>
#include <hip/hip_fp16.h>

// Shapes (fixed by the problem)
#define LL 192
#define FF 2048

typedef __attribute__((__ext_vector_type__(8)))  __bf16 bf16x8;
typedef __attribute__((__ext_vector_type__(4)))  __bf16 bf16x4;
typedef __attribute__((__ext_vector_type__(4)))  float  f32x4;
typedef __attribute__((__ext_vector_type__(2)))  _Float16 f16x2;

#define MFMA16(a, b, c) __builtin_amdgcn_mfma_f32_16x16x32_bf16((a), (b), (c), 0, 0, 0)

// Empirical gfx950 laws (R1-R13 evidence):
//  - OCCUPANCY CLIFF AT 128 VGPR (m69 quantum 64/128/256): R10 @120 VGPR
//    ran 20% occ / 117us; R11 @152 and R12 @156 both 11% occ / 157us with
//    WILDLY different staging -> the staging never mattered, the cliff did.
//    Keep score_kernel's reported VGPR <= 128 at all costs.
//  - Cliff culprits: full lsc unroll (+48: two live acc sets), P[4] (+32).
//  - R11 win kept: packed-f16 DPP quad reduce + pk_mul cut VALU 69->47us.
//  - Grid 1024 = 256 CU x 4 blocks: full co-residency at 4 waves/SIMD;
//    cross-wave overlap (not in-wave ILP) hides epilogue VALU.

// DPP control must be a compile-time constant -> template parameter.
template<int CTL>
__device__ __forceinline__ unsigned dppu(unsigned x) {
    return (unsigned)__builtin_amdgcn_mov_dpp((int)x, CTL, 0xF, 0xF, true);
}
__device__ __forceinline__ unsigned pkrtz_u(float a, float b) {
    return __builtin_bit_cast(unsigned, __builtin_amdgcn_cvt_pkrtz(a, b));
}
__device__ __forceinline__ unsigned hmax2u(unsigned a, unsigned b) {
    unsigned r;
    asm("v_pk_max_f16 %0, %1, %2" : "=v"(r) : "v"(a), "v"(b));
    return r;
}

// ---------------------------------------------------------------------------
// Kernel 1: fused projection + prep (unchanged from R10).
// ---------------------------------------------------------------------------
__launch_bounds__(256, 2)
__global__ void proj_prep_kernel(const float* __restrict__ qf_in,
                                 const float* __restrict__ gf_in,
                                 const float* __restrict__ fc0w,
                                 const float* __restrict__ fc0b,
                                 const float* __restrict__ se,
                                 const float* __restrict__ fc2w,
                                 const float* __restrict__ fc2b,
                                 const float* __restrict__ bn2g,
                                 const float* __restrict__ bn2b,
                                 const float* __restrict__ fc3w,
                                 __bf16* __restrict__ kfragA,
                                 __bf16* __restrict__ qfrag16,
                                 float* __restrict__ sig32,
                                 __bf16* __restrict__ fc2w_bf,
                                 float* __restrict__ h2,
                                 float* __restrict__ bb2,
                                 float* __restrict__ f3)
{
    int bx = blockIdx.x, tid = threadIdx.x;
    if (bx >= 1152) {
        int i0 = (bx - 1152) * 256 + tid;
        const int stride = 160 * 256;
        const float c1 = rsqrtf(1.f + 1e-5f);
        for (int i = i0; i < LL * LL; i += stride) {
            int r = i & 3, lane = (i >> 2) & 63, tile = i >> 8;
            int jt = tile % 12, st = tile / 12;
            int s = st * 16 + (lane >> 4) * 4 + r;
            int t = jt * 16 + (lane & 15);
            sig32[i] = 1.f / (1.f + __expf(-se[s * 192 + t]));
        }
        for (int i = i0; i < FF * LL; i += stride)
            fc2w_bf[i] = (__bf16)fc2w[i];
        for (int i = i0; i < FF; i += stride) {
            float h = bn2g[i] * c1;
            h2[i]  = h;
            bb2[i] = fc2b[i] * h + bn2b[i];
            f3[i]  = fc3w[i];
        }
        return;
    }
    __shared__ __bf16 Xs[32][136];
    __shared__ __bf16 Ws[128][136];
    __shared__ __bf16 Os[4096];
    const float* src = (bx < 384) ? (qf_in + (size_t)bx * (32 * 128))
                                  : (gf_in + (size_t)(bx - 384) * (32 * 128));
#pragma unroll
    for (int it = 0; it < 4; ++it) {
        int e = (it * 256 + tid) * 4;
        int r = e >> 7, c = e & 127;
        float4 v = *reinterpret_cast<const float4*>(src + e);
        bf16x4 xv;
        xv[0] = (__bf16)v.x; xv[1] = (__bf16)v.y;
        xv[2] = (__bf16)v.z; xv[3] = (__bf16)v.w;
        *reinterpret_cast<bf16x4*>(&Xs[r][c]) = xv;
    }
#pragma unroll
    for (int it = 0; it < 16; ++it) {
        int e = (it * 256 + tid) * 4;
        int r = e >> 7, c = e & 127;
        float4 v = *reinterpret_cast<const float4*>(fc0w + e);
        bf16x4 xv;
        xv[0] = (__bf16)v.x; xv[1] = (__bf16)v.y;
        xv[2] = (__bf16)v.z; xv[3] = (__bf16)v.w;
        *reinterpret_cast<bf16x4*>(&Ws[r][c]) = xv;
    }
    __syncthreads();

    int wv = tid >> 6, lane = tid & 63, quad = lane >> 4, l16 = lane & 15;
    int n0 = wv * 32;
    f32x4 acc[2][2];
#pragma unroll
    for (int m = 0; m < 2; ++m)
#pragma unroll
        for (int n = 0; n < 2; ++n) acc[m][n] = (f32x4){0.f, 0.f, 0.f, 0.f};
#pragma unroll
    for (int ks = 0; ks < 4; ++ks) {
        bf16x8 a0 = *reinterpret_cast<const bf16x8*>(&Xs[l16][ks * 32 + quad * 8]);
        bf16x8 a1 = *reinterpret_cast<const bf16x8*>(&Xs[16 + l16][ks * 32 + quad * 8]);
        bf16x8 b0 = *reinterpret_cast<const bf16x8*>(&Ws[n0 + l16][ks * 32 + quad * 8]);
        bf16x8 b1 = *reinterpret_cast<const bf16x8*>(&Ws[n0 + 16 + l16][ks * 32 + quad * 8]);
        acc[0][0] = MFMA16(a0, b0, acc[0][0]);
        acc[0][1] = MFMA16(a0, b1, acc[0][1]);
        acc[1][0] = MFMA16(a1, b0, acc[1][0]);
        acc[1][1] = MFMA16(a1, b1, acc[1][1]);
    }
#pragma unroll
    for (int mt = 0; mt < 2; ++mt)
#pragma unroll
        for (int nt = 0; nt < 2; ++nt) {
            int d = n0 + nt * 16 + l16;
            float bv = fc0b[d];
            int abase = mt * 2048 + (d >> 5) * 512 + ((d >> 3) & 3) * 128 + (d & 7);
#pragma unroll
            for (int r = 0; r < 4; ++r)
                Os[abase + (quad * 4 + r) * 8] = (__bf16)(acc[mt][nt][r] + bv);
        }
    __syncthreads();

    int row0 = bx * 32;
    __bf16* dst;
    if (bx < 384) {
        int qi = row0 / 192, tg0 = (row0 % 192) >> 4;
        dst = qfrag16 + qi * 24576 + tg0 * 2048;
    } else {
        int rk0 = row0 - 12288;
        int ki = rk0 / 192, sg0 = (rk0 % 192) >> 4;
        dst = kfragA + ki * 24576 + sg0 * 2048;
    }
#pragma unroll
    for (int it = 0; it < 2; ++it) {
        int e = (it * 256 + tid) * 8;
        *reinterpret_cast<bf16x8*>(dst + e) =
            *reinterpret_cast<const bf16x8*>(&Os[e]);
    }
}

// ---------------------------------------------------------------------------
// Kernel 2: score GEMM + sigmoid-modulation + dual max-reduce (R13).
//    Grid 1024: block owns (q0, q0+1) x 4 keys.  256 threads = 4 waves,
//    wave w owns fixed t-slice {3w..3w+2}:
//      - B (query) frags for BOTH q hoisted (96 VGPRs, amortized 4 keys)
//      - A (key) staged per third R10-style: global->reg->ds_write in one
//        statement; the compiler hoists the loads. NO explicit prefetch
//        regs, NO lsc unroll -> reported VGPR stays under the 128 cliff.
//      - ks=0 MFMA uses a zero C operand (no 48-reg acc zero-init)
//      - packed-f16 DPP quad reduce + pk_mul epilogue (R11, proven:
//        VALU 69us -> 47us)
//    LDS 28,928 B.
// ---------------------------------------------------------------------------
__launch_bounds__(256, 1)
__global__ void score_kernel(const __bf16* __restrict__ kfragA,
                             const __bf16* __restrict__ qfrag16,
                             const float* __restrict__ sig32,
                             const float* __restrict__ bn1g,
                             const float* __restrict__ bn1b,
                             __bf16* __restrict__ Sred)
{
    __shared__ __bf16 Abuf[8192];          // 16,384 B: 64 s-rows of K frags
    __shared__ unsigned rowP[2][16][98];   // 12,544 B: f16x2 row-pair partials

    int tid = threadIdx.x;
    int q0 = (blockIdx.x & 31) * 2;
    int kbase = (blockIdx.x >> 5) << 2;    // 32 k-groups of 4 keys
    int w = tid >> 6, lane = tid & 63, quad = lane >> 4, l16 = lane & 15;
    const float g1c = bn1g[0] * rsqrtf(1.f + 1e-5f);
    const float b1v = bn1b[0];
    const f32x4 Z4 = (f32x4){0.f, 0.f, 0.f, 0.f};

    // Hoist B (query) fragments for both q: 2 x 12 x 4 = 96 VGPRs
    bf16x8 Bf[2][3][4];
#pragma unroll
    for (int p = 0; p < 2; ++p) {
        const __bf16* qb = qfrag16 + (size_t)(q0 + p) * 24576 + lane * 8;
#pragma unroll
        for (int j = 0; j < 3; ++j)
#pragma unroll
            for (int ks = 0; ks < 4; ++ks)
                Bf[p][j][ks] = *reinterpret_cast<const bf16x8*>(
                    qb + ((3 * w + j) * 4 + ks) * 512);
    }

#pragma unroll 1
    for (int kk = 0; kk < 4; ++kk) {
        int kidx = kbase + kk;
        const __bf16* kp = kfragA + (size_t)kidx * 24576;
        float cm[2][3];
#pragma unroll
        for (int p = 0; p < 2; ++p)
#pragma unroll
            for (int j = 0; j < 3; ++j) cm[p][j] = -3.0e38f;

#pragma unroll 1
        for (int h = 0; h < 3; ++h) {
            // stage third h: s-rows [64h, 64h+64) = 8192 bf16.
            // Single-statement copy: compiler hoists the 4 global loads
            // above this point and batches the ds_writes (R10-proven).
#pragma unroll
            for (int it = 0; it < 4; ++it) {
                int e = (it * 256 + tid) * 8;
                *reinterpret_cast<bf16x8*>(&Abuf[e]) =
                    *reinterpret_cast<const bf16x8*>(kp + 8192 * h + e);
            }
            __syncthreads();   // Abuf ready (prev-third reads done)

#pragma unroll 1
            for (int lsc = 0; lsc < 2; ++lsc) {   // 32 s-rows per chunk
                f32x4 acc[2][2][3];               // [q][i][j]

#pragma unroll
                for (int ks = 0; ks < 4; ++ks) {
                    bf16x8 a0 = *reinterpret_cast<const bf16x8*>(
                        &Abuf[((lsc * 2 + 0) * 4 + ks) * 512 + lane * 8]);
                    bf16x8 a1 = *reinterpret_cast<const bf16x8*>(
                        &Abuf[((lsc * 2 + 1) * 4 + ks) * 512 + lane * 8]);
                    if (ks == 0) {
#pragma unroll
                        for (int j = 0; j < 3; ++j) {
                            acc[0][0][j] = MFMA16(a0, Bf[0][j][0], Z4);
                            acc[0][1][j] = MFMA16(a1, Bf[0][j][0], Z4);
                            acc[1][0][j] = MFMA16(a0, Bf[1][j][0], Z4);
                            acc[1][1][j] = MFMA16(a1, Bf[1][j][0], Z4);
                        }
                    } else {
#pragma unroll
                        for (int j = 0; j < 3; ++j) {
                            acc[0][0][j] = MFMA16(a0, Bf[0][j][ks], acc[0][0][j]);
                            acc[0][1][j] = MFMA16(a1, Bf[0][j][ks], acc[0][1][j]);
                            acc[1][0][j] = MFMA16(a0, Bf[1][j][ks], acc[1][0][j]);
                            acc[1][1][j] = MFMA16(a1, Bf[1][j][ks], acc[1][1][j]);
                        }
                    }
                }

                // epilogue: v = acc * sig (vector mul -> v_pk_mul_f32)
                //   s = 64h + lsc*32 + 16i + quad*4 + r,  t = (3w+j)*16 + l16
#pragma unroll
                for (int i = 0; i < 2; ++i) {
                    int stile = 4 * h + lsc * 2 + i;
                    const float* sp = sig32 +
                        ((size_t)(stile * 12 + 3 * w) * 64 + lane) * 4;
                    f32x4 s0 = *reinterpret_cast<const f32x4*>(sp);
                    f32x4 s1 = *reinterpret_cast<const f32x4*>(sp + 256);
                    f32x4 s2 = *reinterpret_cast<const f32x4*>(sp + 512);
#pragma unroll
                    for (int p = 0; p < 2; ++p) {
                        f32x4 v0 = acc[p][i][0] * s0;
                        f32x4 v1 = acc[p][i][1] * s1;
                        f32x4 v2 = acc[p][i][2] * s2;
                        // col maxes over r folded into running cm (v_max3)
                        cm[p][0] = fmaxf(fmaxf(cm[p][0], fmaxf(v0[0], v0[1])),
                                         fmaxf(v0[2], v0[3]));
                        cm[p][1] = fmaxf(fmaxf(cm[p][1], fmaxf(v1[0], v1[1])),
                                         fmaxf(v1[2], v1[3]));
                        cm[p][2] = fmaxf(fmaxf(cm[p][2], fmaxf(v2[0], v2[1])),
                                         fmaxf(v2[2], v2[3]));
                        // row maxes over j (v_max3), pack row-pairs to f16
                        // (RTZ is monotone: max of rtz == rtz of max)
                        unsigned h01 = pkrtz_u(
                            fmaxf(fmaxf(v0[0], v1[0]), v2[0]),
                            fmaxf(fmaxf(v0[1], v1[1]), v2[1]));
                        unsigned h23 = pkrtz_u(
                            fmaxf(fmaxf(v0[2], v1[2]), v2[2]),
                            fmaxf(fmaxf(v0[3], v1[3]), v2[3]));
                        // quad reduce over l16 bits 0,1: DPP + v_pk_max_f16
                        // 0xB1 = quad_perm [1,0,3,2] (xor1),
                        // 0x4E = quad_perm [2,3,0,1] (xor2)
                        h01 = hmax2u(h01, dppu<0xB1>(h01));
                        h01 = hmax2u(h01, dppu<0x4E>(h01));
                        h23 = hmax2u(h23, dppu<0xB1>(h23));
                        h23 = hmax2u(h23, dppu<0x4E>(h23));
                        if ((l16 & 3) == 0) {
                            int rp = stile * 8 + quad * 2;
                            rowP[p][(l16 >> 2) * 4 + w][rp]     = h01;
                            rowP[p][(l16 >> 2) * 4 + w][rp + 1] = h23;
                        }
                    }
                }
            }
            __syncthreads();   // third consumed; (h=2): rowP fully written
        }

        // col-max (max over s, indexed by t): reduce over quad, direct write
#pragma unroll
        for (int p = 0; p < 2; ++p) {
            size_t ob = (size_t)((q0 + p) * 128 + kidx) * 384;
            float v0 = cm[p][0], v1 = cm[p][1], v2 = cm[p][2];
            v0 = fmaxf(v0, __shfl_xor(v0, 16, 64));
            v0 = fmaxf(v0, __shfl_xor(v0, 32, 64));
            v1 = fmaxf(v1, __shfl_xor(v1, 16, 64));
            v1 = fmaxf(v1, __shfl_xor(v1, 32, 64));
            v2 = fmaxf(v2, __shfl_xor(v2, 16, 64));
            v2 = fmaxf(v2, __shfl_xor(v2, 32, 64));
            if (quad == 0) {
                Sred[ob + (3 * w + 0) * 16 + l16] = (__bf16)(v0 * g1c + b1v);
                Sred[ob + (3 * w + 1) * 16 + l16] = (__bf16)(v1 * g1c + b1v);
                Sred[ob + (3 * w + 2) * 16 + l16] = (__bf16)(v2 * g1c + b1v);
            }
        }

        // row-max combine (max over t, indexed by s) for both q; rowP is
        // complete per the barrier ending h=2; next key's rowP writes are
        // fenced by its staging barrier -> no WAR hazard.
        if (tid < 96) {
#pragma unroll
            for (int p = 0; p < 2; ++p) {
                size_t ob = (size_t)((q0 + p) * 128 + kidx) * 384;
                unsigned m = rowP[p][0][tid];
#pragma unroll
                for (int c = 1; c < 16; ++c)
                    m = hmax2u(m, rowP[p][c][tid]);
                __half2 hm = __builtin_bit_cast(__half2, m);
                float lo = __low2float(hm), hi = __high2float(hm);
                unsigned two =
                    (unsigned)__builtin_bit_cast(unsigned short,
                        (__bf16)(lo * g1c + b1v)) |
                    ((unsigned)__builtin_bit_cast(unsigned short,
                        (__bf16)(hi * g1c + b1v)) << 16);
                *reinterpret_cast<unsigned*>(&Sred[ob + 192 + 2 * tid]) = two;
            }
        }
    }
}

// ---------------------------------------------------------------------------
// Kernel 3: fused fc2 + bn2 + relu + fc3 + pair-sum + bn3 (unchanged).
// ---------------------------------------------------------------------------
__launch_bounds__(512, 1)
__global__ void mlp_kernel(const __bf16* __restrict__ Sred,
                           const __bf16* __restrict__ fc2w_bf,
                           const float* __restrict__ h2,
                           const float* __restrict__ bb2,
                           const float* __restrict__ f3,
                           const float* __restrict__ fc3b,
                           const float* __restrict__ bn3g,
                           const float* __restrict__ bn3b,
                           float* __restrict__ out)
{
    __shared__ __bf16 As[64][200];
    __shared__ float  psum_lds[8][64];
    int bx = blockIdx.x, tid = threadIdx.x;
    const __bf16* asrc = Sred + (size_t)bx * (64 * 192);
#pragma unroll
    for (int it = 0; it < 3; ++it) {
        int e = (it * 512 + tid) * 8;
        int r = e / 192, c = e - r * 192;
        *reinterpret_cast<bf16x8*>(&As[r][c]) =
            *reinterpret_cast<const bf16x8*>(asrc + e);
    }
    __syncthreads();

    int wv = tid >> 6, lane = tid & 63, quad = lane >> 4, l16 = lane & 15;
    bf16x8 af[4][6];
#pragma unroll
    for (int m = 0; m < 4; ++m)
#pragma unroll
        for (int kk = 0; kk < 6; ++kk)
            af[m][kk] = *reinterpret_cast<const bf16x8*>(
                &As[m * 16 + l16][kk * 32 + quad * 8]);

    float ps[4][4] = {{0.f,0.f,0.f,0.f},{0.f,0.f,0.f,0.f},
                      {0.f,0.f,0.f,0.f},{0.f,0.f,0.f,0.f}};
    for (int nt = 0; nt < 16; ++nt) {
        int n0 = wv * 256 + nt * 16;
        f32x4 acc[4];
#pragma unroll
        for (int m = 0; m < 4; ++m) acc[m] = (f32x4){0.f, 0.f, 0.f, 0.f};
        const __bf16* bp = fc2w_bf + (size_t)(n0 + l16) * 192 + quad * 8;
#pragma unroll
        for (int kk = 0; kk < 6; ++kk) {
            bf16x8 b = *reinterpret_cast<const bf16x8*>(bp + kk * 32);
#pragma unroll
            for (int m = 0; m < 4; ++m) acc[m] = MFMA16(af[m][kk], b, acc[m]);
        }
        int n = n0 + l16;
        float hh = h2[n], bb = bb2[n], ffv = f3[n];
#pragma unroll
        for (int m = 0; m < 4; ++m)
#pragma unroll
            for (int r = 0; r < 4; ++r)
                ps[m][r] += fmaxf(acc[m][r] * hh + bb, 0.f) * ffv;
    }
#pragma unroll
    for (int m = 0; m < 4; ++m)
#pragma unroll
        for (int r = 0; r < 4; ++r) {
            float v = ps[m][r];
            v += __shfl_xor(v, 1, 64);
            v += __shfl_xor(v, 2, 64);
            v += __shfl_xor(v, 4, 64);
            v += __shfl_xor(v, 8, 64);
            if (l16 == 0) psum_lds[wv][m * 16 + quad * 4 + r] = v;
        }
    __syncthreads();
    if (tid < 32) {
        float s = 0.f;
#pragma unroll
        for (int w = 0; w < 8; ++w)
            s += psum_lds[w][2 * tid] + psum_lds[w][2 * tid + 1];
        const float c1 = rsqrtf(1.f + 1e-5f);
        out[bx * 32 + tid] = (s + 2.f * fc3b[0]) * (bn3g[0] * c1) + bn3b[0];
    }
}

// ---------------------------------------------------------------------------
extern "C" void kernel_launch(void* const* d_in, const int* in_sizes, int n_in,
                              void* d_out, int out_size, void* d_ws, size_t ws_size,
                              hipStream_t stream)
{
    const float* q_feat = (const float*)d_in[0];
    const float* g_feat = (const float*)d_in[1];
    const float* se     = (const float*)d_in[2];
    const float* fc0w   = (const float*)d_in[3];
    const float* fc0b   = (const float*)d_in[4];
    const float* fc2w   = (const float*)d_in[5];
    const float* fc2b   = (const float*)d_in[6];
    const float* fc3w   = (const float*)d_in[7];
    const float* fc3b   = (const float*)d_in[8];
    const float* bn1g   = (const float*)d_in[9];
    const float* bn1b   = (const float*)d_in[10];
    const float* bn2g   = (const float*)d_in[11];
    const float* bn2b   = (const float*)d_in[12];
    const float* bn3g   = (const float*)d_in[13];
    const float* bn3b   = (const float*)d_in[14];
    float* out = (float*)d_out;

    char* ws = (char*)d_ws;
    __bf16* kfragA   = (__bf16*)(ws);                 //  6,291,456 B
    __bf16* qfrag16  = (__bf16*)(ws +  6291456);      //  3,145,728 B
    float*  sig32    = (float*) (ws +  9437184);      //    147,456 B
    __bf16* fc2w_bf  = (__bf16*)(ws +  9584640);      //    786,432 B
    float*  h2       = (float*) (ws + 10371072);      //      8,192 B
    float*  bb2      = (float*) (ws + 10379264);      //      8,192 B
    float*  f3       = (float*) (ws + 10387456);      //      8,192 B
    __bf16* Sred     = (__bf16*)(ws + 10395648);      //  6,291,456 B (16.69 MB total)

    proj_prep_kernel<<<1312, 256, 0, stream>>>(q_feat, g_feat, fc0w, fc0b, se,
                                               fc2w, fc2b, bn2g, bn2b, fc3w,
                                               kfragA, qfrag16, sig32, fc2w_bf,
                                               h2, bb2, f3);
    score_kernel<<<1024, 256, 0, stream>>>(kfragA, qfrag16, sig32, bn1g, bn1b, Sred);
    mlp_kernel<<<256, 512, 0, stream>>>(Sred, fc2w_bf, h2, bb2, f3,
                                        fc3b, bn3g, bn3b, out);
}

// Round 5
// 224.957 us; speedup vs baseline: 1.1450x; 1.1450x over previous
//
#include <hip/hip_runtime.h>
#include <hip/hip_fp16.h>

// Shapes (fixed by the problem)
#define LL 192
#define FF 2048

typedef __attribute__((__ext_vector_type__(8)))  __bf16 bf16x8;
typedef __attribute__((__ext_vector_type__(4)))  __bf16 bf16x4;
typedef __attribute__((__ext_vector_type__(4)))  float  f32x4;
typedef __attribute__((__ext_vector_type__(2)))  _Float16 f16x2;

#define MFMA16(a, b, c) __builtin_amdgcn_mfma_f32_16x16x32_bf16((a), (b), (c), 0, 0, 0)

// Empirical gfx950 laws (R1-R14 evidence):
//  - OCCUPANCY CLIFF AT 128 VGPR (m69 quantum 64/128/256): 120 VGPR -> 20%
//    occ; 132/152/156 VGPR -> 11% occ, +35us. R13 missed by 4 regs (132).
//    R14: force the cap with __launch_bounds__(256,2) = 128 VGPR budget.
//  - R11 win kept: packed-f16 DPP quad reduce + pk_mul cut VALU 69->47us.
//  - Grid 1024 = 256 CU x 4 blocks: full co-residency at 4 waves/SIMD;
//    cross-wave overlap (not in-wave ILP) hides epilogue VALU.

// DPP control must be a compile-time constant -> template parameter.
template<int CTL>
__device__ __forceinline__ unsigned dppu(unsigned x) {
    return (unsigned)__builtin_amdgcn_mov_dpp((int)x, CTL, 0xF, 0xF, true);
}
__device__ __forceinline__ unsigned pkrtz_u(float a, float b) {
    return __builtin_bit_cast(unsigned, __builtin_amdgcn_cvt_pkrtz(a, b));
}
__device__ __forceinline__ unsigned hmax2u(unsigned a, unsigned b) {
    unsigned r;
    asm("v_pk_max_f16 %0, %1, %2" : "=v"(r) : "v"(a), "v"(b));
    return r;
}

// ---------------------------------------------------------------------------
// Kernel 1: fused projection + prep (unchanged from R10).
// ---------------------------------------------------------------------------
__launch_bounds__(256, 2)
__global__ void proj_prep_kernel(const float* __restrict__ qf_in,
                                 const float* __restrict__ gf_in,
                                 const float* __restrict__ fc0w,
                                 const float* __restrict__ fc0b,
                                 const float* __restrict__ se,
                                 const float* __restrict__ fc2w,
                                 const float* __restrict__ fc2b,
                                 const float* __restrict__ bn2g,
                                 const float* __restrict__ bn2b,
                                 const float* __restrict__ fc3w,
                                 __bf16* __restrict__ kfragA,
                                 __bf16* __restrict__ qfrag16,
                                 float* __restrict__ sig32,
                                 __bf16* __restrict__ fc2w_bf,
                                 float* __restrict__ h2,
                                 float* __restrict__ bb2,
                                 float* __restrict__ f3)
{
    int bx = blockIdx.x, tid = threadIdx.x;
    if (bx >= 1152) {
        int i0 = (bx - 1152) * 256 + tid;
        const int stride = 160 * 256;
        const float c1 = rsqrtf(1.f + 1e-5f);
        for (int i = i0; i < LL * LL; i += stride) {
            int r = i & 3, lane = (i >> 2) & 63, tile = i >> 8;
            int jt = tile % 12, st = tile / 12;
            int s = st * 16 + (lane >> 4) * 4 + r;
            int t = jt * 16 + (lane & 15);
            sig32[i] = 1.f / (1.f + __expf(-se[s * 192 + t]));
        }
        for (int i = i0; i < FF * LL; i += stride)
            fc2w_bf[i] = (__bf16)fc2w[i];
        for (int i = i0; i < FF; i += stride) {
            float h = bn2g[i] * c1;
            h2[i]  = h;
            bb2[i] = fc2b[i] * h + bn2b[i];
            f3[i]  = fc3w[i];
        }
        return;
    }
    __shared__ __bf16 Xs[32][136];
    __shared__ __bf16 Ws[128][136];
    __shared__ __bf16 Os[4096];
    const float* src = (bx < 384) ? (qf_in + (size_t)bx * (32 * 128))
                                  : (gf_in + (size_t)(bx - 384) * (32 * 128));
#pragma unroll
    for (int it = 0; it < 4; ++it) {
        int e = (it * 256 + tid) * 4;
        int r = e >> 7, c = e & 127;
        float4 v = *reinterpret_cast<const float4*>(src + e);
        bf16x4 xv;
        xv[0] = (__bf16)v.x; xv[1] = (__bf16)v.y;
        xv[2] = (__bf16)v.z; xv[3] = (__bf16)v.w;
        *reinterpret_cast<bf16x4*>(&Xs[r][c]) = xv;
    }
#pragma unroll
    for (int it = 0; it < 16; ++it) {
        int e = (it * 256 + tid) * 4;
        int r = e >> 7, c = e & 127;
        float4 v = *reinterpret_cast<const float4*>(fc0w + e);
        bf16x4 xv;
        xv[0] = (__bf16)v.x; xv[1] = (__bf16)v.y;
        xv[2] = (__bf16)v.z; xv[3] = (__bf16)v.w;
        *reinterpret_cast<bf16x4*>(&Ws[r][c]) = xv;
    }
    __syncthreads();

    int wv = tid >> 6, lane = tid & 63, quad = lane >> 4, l16 = lane & 15;
    int n0 = wv * 32;
    f32x4 acc[2][2];
#pragma unroll
    for (int m = 0; m < 2; ++m)
#pragma unroll
        for (int n = 0; n < 2; ++n) acc[m][n] = (f32x4){0.f, 0.f, 0.f, 0.f};
#pragma unroll
    for (int ks = 0; ks < 4; ++ks) {
        bf16x8 a0 = *reinterpret_cast<const bf16x8*>(&Xs[l16][ks * 32 + quad * 8]);
        bf16x8 a1 = *reinterpret_cast<const bf16x8*>(&Xs[16 + l16][ks * 32 + quad * 8]);
        bf16x8 b0 = *reinterpret_cast<const bf16x8*>(&Ws[n0 + l16][ks * 32 + quad * 8]);
        bf16x8 b1 = *reinterpret_cast<const bf16x8*>(&Ws[n0 + 16 + l16][ks * 32 + quad * 8]);
        acc[0][0] = MFMA16(a0, b0, acc[0][0]);
        acc[0][1] = MFMA16(a0, b1, acc[0][1]);
        acc[1][0] = MFMA16(a1, b0, acc[1][0]);
        acc[1][1] = MFMA16(a1, b1, acc[1][1]);
    }
#pragma unroll
    for (int mt = 0; mt < 2; ++mt)
#pragma unroll
        for (int nt = 0; nt < 2; ++nt) {
            int d = n0 + nt * 16 + l16;
            float bv = fc0b[d];
            int abase = mt * 2048 + (d >> 5) * 512 + ((d >> 3) & 3) * 128 + (d & 7);
#pragma unroll
            for (int r = 0; r < 4; ++r)
                Os[abase + (quad * 4 + r) * 8] = (__bf16)(acc[mt][nt][r] + bv);
        }
    __syncthreads();

    int row0 = bx * 32;
    __bf16* dst;
    if (bx < 384) {
        int qi = row0 / 192, tg0 = (row0 % 192) >> 4;
        dst = qfrag16 + qi * 24576 + tg0 * 2048;
    } else {
        int rk0 = row0 - 12288;
        int ki = rk0 / 192, sg0 = (rk0 % 192) >> 4;
        dst = kfragA + ki * 24576 + sg0 * 2048;
    }
#pragma unroll
    for (int it = 0; it < 2; ++it) {
        int e = (it * 256 + tid) * 8;
        *reinterpret_cast<bf16x8*>(dst + e) =
            *reinterpret_cast<const bf16x8*>(&Os[e]);
    }
}

// ---------------------------------------------------------------------------
// Kernel 2: score GEMM + sigmoid-modulation + dual max-reduce (R14).
//    Grid 1024: block owns (q0, q0+1) x 4 keys.  256 threads = 4 waves,
//    wave w owns fixed t-slice {3w..3w+2}:
//      - B (query) frags for BOTH q hoisted (96 VGPRs, amortized 4 keys)
//      - A (key) staged per third R10-style: global->reg->ds_write; the
//        compiler hoists the loads above the barrier.
//      - ks=0 MFMA uses a zero C operand (no 48-reg acc zero-init)
//      - packed-f16 DPP quad reduce + pk_mul epilogue (R11, proven)
//      - __launch_bounds__(256,2): HARD 128-VGPR cap -> 4 waves/SIMD.
//    LDS 28,928 B.
// ---------------------------------------------------------------------------
__launch_bounds__(256, 2)
__global__ void score_kernel(const __bf16* __restrict__ kfragA,
                             const __bf16* __restrict__ qfrag16,
                             const float* __restrict__ sig32,
                             const float* __restrict__ bn1g,
                             const float* __restrict__ bn1b,
                             __bf16* __restrict__ Sred)
{
    __shared__ __bf16 Abuf[8192];          // 16,384 B: 64 s-rows of K frags
    __shared__ unsigned rowP[2][16][98];   // 12,544 B: f16x2 row-pair partials

    int tid = threadIdx.x;
    int q0 = (blockIdx.x & 31) * 2;
    int kbase = (blockIdx.x >> 5) << 2;    // 32 k-groups of 4 keys
    int w = tid >> 6, lane = tid & 63, quad = lane >> 4, l16 = lane & 15;
    const float g1c = bn1g[0] * rsqrtf(1.f + 1e-5f);
    const float b1v = bn1b[0];
    // per-thread sig base: offset ((stile*12+3w)*64+lane)*4 floats
    //   = stile*3072 + (768*w + 4*lane)
    const float* sigb = sig32 + 768 * w + 4 * lane;

    // Hoist B (query) fragments for both q: 2 x 12 x 4 = 96 VGPRs
    bf16x8 Bf[2][3][4];
#pragma unroll
    for (int p = 0; p < 2; ++p) {
        const __bf16* qb = qfrag16 + (size_t)(q0 + p) * 24576 + lane * 8;
#pragma unroll
        for (int j = 0; j < 3; ++j)
#pragma unroll
            for (int ks = 0; ks < 4; ++ks)
                Bf[p][j][ks] = *reinterpret_cast<const bf16x8*>(
                    qb + ((3 * w + j) * 4 + ks) * 512);
    }

#pragma unroll 1
    for (int kk = 0; kk < 4; ++kk) {
        int kidx = kbase + kk;
        const __bf16* kp = kfragA + (size_t)kidx * 24576;
        float cm[2][3];
#pragma unroll
        for (int p = 0; p < 2; ++p)
#pragma unroll
            for (int j = 0; j < 3; ++j) cm[p][j] = -3.0e38f;

#pragma unroll 1
        for (int h = 0; h < 3; ++h) {
            // stage third h: s-rows [64h, 64h+64) = 8192 bf16.
            // Single-statement copy: compiler hoists the 4 global loads
            // above this point and batches the ds_writes (R10-proven).
#pragma unroll
            for (int it = 0; it < 4; ++it) {
                int e = (it * 256 + tid) * 8;
                *reinterpret_cast<bf16x8*>(&Abuf[e]) =
                    *reinterpret_cast<const bf16x8*>(kp + 8192 * h + e);
            }
            __syncthreads();   // Abuf ready (prev-third reads done)

#pragma unroll 1
            for (int lsc = 0; lsc < 2; ++lsc) {   // 32 s-rows per chunk
                f32x4 acc[2][2][3];               // [q][i][j]

#pragma unroll
                for (int ks = 0; ks < 4; ++ks) {
                    bf16x8 a0 = *reinterpret_cast<const bf16x8*>(
                        &Abuf[((lsc * 2 + 0) * 4 + ks) * 512 + lane * 8]);
                    bf16x8 a1 = *reinterpret_cast<const bf16x8*>(
                        &Abuf[((lsc * 2 + 1) * 4 + ks) * 512 + lane * 8]);
                    if (ks == 0) {
                        const f32x4 Z4 = (f32x4){0.f, 0.f, 0.f, 0.f};
#pragma unroll
                        for (int j = 0; j < 3; ++j) {
                            acc[0][0][j] = MFMA16(a0, Bf[0][j][0], Z4);
                            acc[0][1][j] = MFMA16(a1, Bf[0][j][0], Z4);
                            acc[1][0][j] = MFMA16(a0, Bf[1][j][0], Z4);
                            acc[1][1][j] = MFMA16(a1, Bf[1][j][0], Z4);
                        }
                    } else {
#pragma unroll
                        for (int j = 0; j < 3; ++j) {
                            acc[0][0][j] = MFMA16(a0, Bf[0][j][ks], acc[0][0][j]);
                            acc[0][1][j] = MFMA16(a1, Bf[0][j][ks], acc[0][1][j]);
                            acc[1][0][j] = MFMA16(a0, Bf[1][j][ks], acc[1][0][j]);
                            acc[1][1][j] = MFMA16(a1, Bf[1][j][ks], acc[1][1][j]);
                        }
                    }
                }

                // epilogue: v = acc * sig (vector mul -> v_pk_mul_f32)
                //   s = 64h + lsc*32 + 16i + quad*4 + r,  t = (3w+j)*16 + l16
#pragma unroll
                for (int i = 0; i < 2; ++i) {
                    int stile = 4 * h + lsc * 2 + i;
                    const float* sp = sigb + stile * 3072;
                    f32x4 s0 = *reinterpret_cast<const f32x4*>(sp);
                    f32x4 s1 = *reinterpret_cast<const f32x4*>(sp + 256);
                    f32x4 s2 = *reinterpret_cast<const f32x4*>(sp + 512);
#pragma unroll
                    for (int p = 0; p < 2; ++p) {
                        f32x4 v0 = acc[p][i][0] * s0;
                        f32x4 v1 = acc[p][i][1] * s1;
                        f32x4 v2 = acc[p][i][2] * s2;
                        // col maxes over r folded into running cm (v_max3)
                        cm[p][0] = fmaxf(fmaxf(cm[p][0], fmaxf(v0[0], v0[1])),
                                         fmaxf(v0[2], v0[3]));
                        cm[p][1] = fmaxf(fmaxf(cm[p][1], fmaxf(v1[0], v1[1])),
                                         fmaxf(v1[2], v1[3]));
                        cm[p][2] = fmaxf(fmaxf(cm[p][2], fmaxf(v2[0], v2[1])),
                                         fmaxf(v2[2], v2[3]));
                        // row maxes over j (v_max3), pack row-pairs to f16
                        // (RTZ is monotone: max of rtz == rtz of max)
                        unsigned h01 = pkrtz_u(
                            fmaxf(fmaxf(v0[0], v1[0]), v2[0]),
                            fmaxf(fmaxf(v0[1], v1[1]), v2[1]));
                        unsigned h23 = pkrtz_u(
                            fmaxf(fmaxf(v0[2], v1[2]), v2[2]),
                            fmaxf(fmaxf(v0[3], v1[3]), v2[3]));
                        // quad reduce over l16 bits 0,1: DPP + v_pk_max_f16
                        // 0xB1 = quad_perm [1,0,3,2] (xor1),
                        // 0x4E = quad_perm [2,3,0,1] (xor2)
                        h01 = hmax2u(h01, dppu<0xB1>(h01));
                        h01 = hmax2u(h01, dppu<0x4E>(h01));
                        h23 = hmax2u(h23, dppu<0xB1>(h23));
                        h23 = hmax2u(h23, dppu<0x4E>(h23));
                        if ((l16 & 3) == 0) {
                            int rp = stile * 8 + quad * 2;
                            rowP[p][(l16 >> 2) * 4 + w][rp]     = h01;
                            rowP[p][(l16 >> 2) * 4 + w][rp + 1] = h23;
                        }
                    }
                }
            }
            __syncthreads();   // third consumed; (h=2): rowP fully written
        }

        // col-max (max over s, indexed by t): reduce over quad, direct write
#pragma unroll
        for (int p = 0; p < 2; ++p) {
            size_t ob = (size_t)((q0 + p) * 128 + kidx) * 384;
            float v0 = cm[p][0], v1 = cm[p][1], v2 = cm[p][2];
            v0 = fmaxf(v0, __shfl_xor(v0, 16, 64));
            v0 = fmaxf(v0, __shfl_xor(v0, 32, 64));
            v1 = fmaxf(v1, __shfl_xor(v1, 16, 64));
            v1 = fmaxf(v1, __shfl_xor(v1, 32, 64));
            v2 = fmaxf(v2, __shfl_xor(v2, 16, 64));
            v2 = fmaxf(v2, __shfl_xor(v2, 32, 64));
            if (quad == 0) {
                Sred[ob + (3 * w + 0) * 16 + l16] = (__bf16)(v0 * g1c + b1v);
                Sred[ob + (3 * w + 1) * 16 + l16] = (__bf16)(v1 * g1c + b1v);
                Sred[ob + (3 * w + 2) * 16 + l16] = (__bf16)(v2 * g1c + b1v);
            }
        }

        // row-max combine (max over t, indexed by s) for both q; rowP is
        // complete per the barrier ending h=2; next key's rowP writes are
        // fenced by its staging barrier -> no WAR hazard.
        if (tid < 96) {
#pragma unroll
            for (int p = 0; p < 2; ++p) {
                size_t ob = (size_t)((q0 + p) * 128 + kidx) * 384;
                unsigned m = rowP[p][0][tid];
#pragma unroll
                for (int c = 1; c < 16; ++c)
                    m = hmax2u(m, rowP[p][c][tid]);
                __half2 hm = __builtin_bit_cast(__half2, m);
                float lo = __low2float(hm), hi = __high2float(hm);
                unsigned two =
                    (unsigned)__builtin_bit_cast(unsigned short,
                        (__bf16)(lo * g1c + b1v)) |
                    ((unsigned)__builtin_bit_cast(unsigned short,
                        (__bf16)(hi * g1c + b1v)) << 16);
                *reinterpret_cast<unsigned*>(&Sred[ob + 192 + 2 * tid]) = two;
            }
        }
    }
}

// ---------------------------------------------------------------------------
// Kernel 3: fused fc2 + bn2 + relu + fc3 + pair-sum + bn3 (unchanged).
// ---------------------------------------------------------------------------
__launch_bounds__(512, 1)
__global__ void mlp_kernel(const __bf16* __restrict__ Sred,
                           const __bf16* __restrict__ fc2w_bf,
                           const float* __restrict__ h2,
                           const float* __restrict__ bb2,
                           const float* __restrict__ f3,
                           const float* __restrict__ fc3b,
                           const float* __restrict__ bn3g,
                           const float* __restrict__ bn3b,
                           float* __restrict__ out)
{
    __shared__ __bf16 As[64][200];
    __shared__ float  psum_lds[8][64];
    int bx = blockIdx.x, tid = threadIdx.x;
    const __bf16* asrc = Sred + (size_t)bx * (64 * 192);
#pragma unroll
    for (int it = 0; it < 3; ++it) {
        int e = (it * 512 + tid) * 8;
        int r = e / 192, c = e - r * 192;
        *reinterpret_cast<bf16x8*>(&As[r][c]) =
            *reinterpret_cast<const bf16x8*>(asrc + e);
    }
    __syncthreads();

    int wv = tid >> 6, lane = tid & 63, quad = lane >> 4, l16 = lane & 15;
    bf16x8 af[4][6];
#pragma unroll
    for (int m = 0; m < 4; ++m)
#pragma unroll
        for (int kk = 0; kk < 6; ++kk)
            af[m][kk] = *reinterpret_cast<const bf16x8*>(
                &As[m * 16 + l16][kk * 32 + quad * 8]);

    float ps[4][4] = {{0.f,0.f,0.f,0.f},{0.f,0.f,0.f,0.f},
                      {0.f,0.f,0.f,0.f},{0.f,0.f,0.f,0.f}};
    for (int nt = 0; nt < 16; ++nt) {
        int n0 = wv * 256 + nt * 16;
        f32x4 acc[4];
#pragma unroll
        for (int m = 0; m < 4; ++m) acc[m] = (f32x4){0.f, 0.f, 0.f, 0.f};
        const __bf16* bp = fc2w_bf + (size_t)(n0 + l16) * 192 + quad * 8;
#pragma unroll
        for (int kk = 0; kk < 6; ++kk) {
            bf16x8 b = *reinterpret_cast<const bf16x8*>(bp + kk * 32);
#pragma unroll
            for (int m = 0; m < 4; ++m) acc[m] = MFMA16(af[m][kk], b, acc[m]);
        }
        int n = n0 + l16;
        float hh = h2[n], bb = bb2[n], ffv = f3[n];
#pragma unroll
        for (int m = 0; m < 4; ++m)
#pragma unroll
            for (int r = 0; r < 4; ++r)
                ps[m][r] += fmaxf(acc[m][r] * hh + bb, 0.f) * ffv;
    }
#pragma unroll
    for (int m = 0; m < 4; ++m)
#pragma unroll
        for (int r = 0; r < 4; ++r) {
            float v = ps[m][r];
            v += __shfl_xor(v, 1, 64);
            v += __shfl_xor(v, 2, 64);
            v += __shfl_xor(v, 4, 64);
            v += __shfl_xor(v, 8, 64);
            if (l16 == 0) psum_lds[wv][m * 16 + quad * 4 + r] = v;
        }
    __syncthreads();
    if (tid < 32) {
        float s = 0.f;
#pragma unroll
        for (int w = 0; w < 8; ++w)
            s += psum_lds[w][2 * tid] + psum_lds[w][2 * tid + 1];
        const float c1 = rsqrtf(1.f + 1e-5f);
        out[bx * 32 + tid] = (s + 2.f * fc3b[0]) * (bn3g[0] * c1) + bn3b[0];
    }
}

// ---------------------------------------------------------------------------
extern "C" void kernel_launch(void* const* d_in, const int* in_sizes, int n_in,
                              void* d_out, int out_size, void* d_ws, size_t ws_size,
                              hipStream_t stream)
{
    const float* q_feat = (const float*)d_in[0];
    const float* g_feat = (const float*)d_in[1];
    const float* se     = (const float*)d_in[2];
    const float* fc0w   = (const float*)d_in[3];
    const float* fc0b   = (const float*)d_in[4];
    const float* fc2w   = (const float*)d_in[5];
    const float* fc2b   = (const float*)d_in[6];
    const float* fc3w   = (const float*)d_in[7];
    const float* fc3b   = (const float*)d_in[8];
    const float* bn1g   = (const float*)d_in[9];
    const float* bn1b   = (const float*)d_in[10];
    const float* bn2g   = (const float*)d_in[11];
    const float* bn2b   = (const float*)d_in[12];
    const float* bn3g   = (const float*)d_in[13];
    const float* bn3b   = (const float*)d_in[14];
    float* out = (float*)d_out;

    char* ws = (char*)d_ws;
    __bf16* kfragA   = (__bf16*)(ws);                 //  6,291,456 B
    __bf16* qfrag16  = (__bf16*)(ws +  6291456);      //  3,145,728 B
    float*  sig32    = (float*) (ws +  9437184);      //    147,456 B
    __bf16* fc2w_bf  = (__bf16*)(ws +  9584640);      //    786,432 B
    float*  h2       = (float*) (ws + 10371072);      //      8,192 B
    float*  bb2      = (float*) (ws + 10379264);      //      8,192 B
    float*  f3       = (float*) (ws + 10387456);      //      8,192 B
    __bf16* Sred     = (__bf16*)(ws + 10395648);      //  6,291,456 B (16.69 MB total)

    proj_prep_kernel<<<1312, 256, 0, stream>>>(q_feat, g_feat, fc0w, fc0b, se,
                                               fc2w, fc2b, bn2g, bn2b, fc3w,
                                               kfragA, qfrag16, sig32, fc2w_bf,
                                               h2, bb2, f3);
    score_kernel<<<1024, 256, 0, stream>>>(kfragA, qfrag16, sig32, bn1g, bn1b, Sred);
    mlp_kernel<<<256, 512, 0, stream>>>(Sred, fc2w_bf, h2, bb2, f3,
                                        fc3b, bn3g, bn3b, out);
}

// Round 6
// 223.020 us; speedup vs baseline: 1.1549x; 1.0087x over previous
//
#include <hip/hip_runtime.h>
#include <hip/hip_fp16.h>

// Shapes (fixed by the problem)
#define LL 192
#define FF 2048

typedef __attribute__((__ext_vector_type__(8)))  __bf16 bf16x8;
typedef __attribute__((__ext_vector_type__(4)))  __bf16 bf16x4;
typedef __attribute__((__ext_vector_type__(4)))  float  f32x4;
typedef __attribute__((__ext_vector_type__(2)))  _Float16 f16x2;

#define MFMA16(a, b, c) __builtin_amdgcn_mfma_f32_16x16x32_bf16((a), (b), (c), 0, 0, 0)

// Empirical gfx950 laws (R1-R15 evidence):
//  - OCCUPANCY CLIFF AT 128 VGPR (m69): must keep budget <=128 via
//    __launch_bounds__(256,2). 108 VGPR @ 21% occ confirmed R14.
//  - R14 audit: VALU cut real (59->35%) but MfmaUtil+VALUBusy = 63% ->
//    37% stall. 24 block-wide barriers (A-tile LDS staging) serialize.
//  - R15: A-fragments are wave-INVARIANT (only Bf differs per wave) and
//    L2-resident -> load A directly from global, delete Abuf + 16
//    barriers. Waves de-phase; cross-wave overlap (m114) fills stalls.
//  - R11 win kept: packed-f16 DPP quad reduce + pk_mul epilogue.

// DPP control must be a compile-time constant -> template parameter.
template<int CTL>
__device__ __forceinline__ unsigned dppu(unsigned x) {
    return (unsigned)__builtin_amdgcn_mov_dpp((int)x, CTL, 0xF, 0xF, true);
}
__device__ __forceinline__ unsigned pkrtz_u(float a, float b) {
    return __builtin_bit_cast(unsigned, __builtin_amdgcn_cvt_pkrtz(a, b));
}
__device__ __forceinline__ unsigned hmax2u(unsigned a, unsigned b) {
    unsigned r;
    asm("v_pk_max_f16 %0, %1, %2" : "=v"(r) : "v"(a), "v"(b));
    return r;
}

// ---------------------------------------------------------------------------
// Kernel 1: fused projection + prep (unchanged from R10).
// ---------------------------------------------------------------------------
__launch_bounds__(256, 2)
__global__ void proj_prep_kernel(const float* __restrict__ qf_in,
                                 const float* __restrict__ gf_in,
                                 const float* __restrict__ fc0w,
                                 const float* __restrict__ fc0b,
                                 const float* __restrict__ se,
                                 const float* __restrict__ fc2w,
                                 const float* __restrict__ fc2b,
                                 const float* __restrict__ bn2g,
                                 const float* __restrict__ bn2b,
                                 const float* __restrict__ fc3w,
                                 __bf16* __restrict__ kfragA,
                                 __bf16* __restrict__ qfrag16,
                                 float* __restrict__ sig32,
                                 __bf16* __restrict__ fc2w_bf,
                                 float* __restrict__ h2,
                                 float* __restrict__ bb2,
                                 float* __restrict__ f3)
{
    int bx = blockIdx.x, tid = threadIdx.x;
    if (bx >= 1152) {
        int i0 = (bx - 1152) * 256 + tid;
        const int stride = 160 * 256;
        const float c1 = rsqrtf(1.f + 1e-5f);
        for (int i = i0; i < LL * LL; i += stride) {
            int r = i & 3, lane = (i >> 2) & 63, tile = i >> 8;
            int jt = tile % 12, st = tile / 12;
            int s = st * 16 + (lane >> 4) * 4 + r;
            int t = jt * 16 + (lane & 15);
            sig32[i] = 1.f / (1.f + __expf(-se[s * 192 + t]));
        }
        for (int i = i0; i < FF * LL; i += stride)
            fc2w_bf[i] = (__bf16)fc2w[i];
        for (int i = i0; i < FF; i += stride) {
            float h = bn2g[i] * c1;
            h2[i]  = h;
            bb2[i] = fc2b[i] * h + bn2b[i];
            f3[i]  = fc3w[i];
        }
        return;
    }
    __shared__ __bf16 Xs[32][136];
    __shared__ __bf16 Ws[128][136];
    __shared__ __bf16 Os[4096];
    const float* src = (bx < 384) ? (qf_in + (size_t)bx * (32 * 128))
                                  : (gf_in + (size_t)(bx - 384) * (32 * 128));
#pragma unroll
    for (int it = 0; it < 4; ++it) {
        int e = (it * 256 + tid) * 4;
        int r = e >> 7, c = e & 127;
        float4 v = *reinterpret_cast<const float4*>(src + e);
        bf16x4 xv;
        xv[0] = (__bf16)v.x; xv[1] = (__bf16)v.y;
        xv[2] = (__bf16)v.z; xv[3] = (__bf16)v.w;
        *reinterpret_cast<bf16x4*>(&Xs[r][c]) = xv;
    }
#pragma unroll
    for (int it = 0; it < 16; ++it) {
        int e = (it * 256 + tid) * 4;
        int r = e >> 7, c = e & 127;
        float4 v = *reinterpret_cast<const float4*>(fc0w + e);
        bf16x4 xv;
        xv[0] = (__bf16)v.x; xv[1] = (__bf16)v.y;
        xv[2] = (__bf16)v.z; xv[3] = (__bf16)v.w;
        *reinterpret_cast<bf16x4*>(&Ws[r][c]) = xv;
    }
    __syncthreads();

    int wv = tid >> 6, lane = tid & 63, quad = lane >> 4, l16 = lane & 15;
    int n0 = wv * 32;
    f32x4 acc[2][2];
#pragma unroll
    for (int m = 0; m < 2; ++m)
#pragma unroll
        for (int n = 0; n < 2; ++n) acc[m][n] = (f32x4){0.f, 0.f, 0.f, 0.f};
#pragma unroll
    for (int ks = 0; ks < 4; ++ks) {
        bf16x8 a0 = *reinterpret_cast<const bf16x8*>(&Xs[l16][ks * 32 + quad * 8]);
        bf16x8 a1 = *reinterpret_cast<const bf16x8*>(&Xs[16 + l16][ks * 32 + quad * 8]);
        bf16x8 b0 = *reinterpret_cast<const bf16x8*>(&Ws[n0 + l16][ks * 32 + quad * 8]);
        bf16x8 b1 = *reinterpret_cast<const bf16x8*>(&Ws[n0 + 16 + l16][ks * 32 + quad * 8]);
        acc[0][0] = MFMA16(a0, b0, acc[0][0]);
        acc[0][1] = MFMA16(a0, b1, acc[0][1]);
        acc[1][0] = MFMA16(a1, b0, acc[1][0]);
        acc[1][1] = MFMA16(a1, b1, acc[1][1]);
    }
#pragma unroll
    for (int mt = 0; mt < 2; ++mt)
#pragma unroll
        for (int nt = 0; nt < 2; ++nt) {
            int d = n0 + nt * 16 + l16;
            float bv = fc0b[d];
            int abase = mt * 2048 + (d >> 5) * 512 + ((d >> 3) & 3) * 128 + (d & 7);
#pragma unroll
            for (int r = 0; r < 4; ++r)
                Os[abase + (quad * 4 + r) * 8] = (__bf16)(acc[mt][nt][r] + bv);
        }
    __syncthreads();

    int row0 = bx * 32;
    __bf16* dst;
    if (bx < 384) {
        int qi = row0 / 192, tg0 = (row0 % 192) >> 4;
        dst = qfrag16 + qi * 24576 + tg0 * 2048;
    } else {
        int rk0 = row0 - 12288;
        int ki = rk0 / 192, sg0 = (rk0 % 192) >> 4;
        dst = kfragA + ki * 24576 + sg0 * 2048;
    }
#pragma unroll
    for (int it = 0; it < 2; ++it) {
        int e = (it * 256 + tid) * 8;
        *reinterpret_cast<bf16x8*>(dst + e) =
            *reinterpret_cast<const bf16x8*>(&Os[e]);
    }
}

// ---------------------------------------------------------------------------
// Kernel 2: score GEMM + sigmoid-modulation + dual max-reduce (R15).
//    Grid 1024: block owns (q0, q0+1) x 4 keys.  256 threads = 4 waves,
//    wave w owns fixed t-slice {3w..3w+2}:
//      - B (query) frags for BOTH q (compiler balances live-vs-reload
//        under the 128-VGPR cap)
//      - A (key) frags loaded DIRECTLY from global (wave-invariant,
//        L2-resident, fragment-ordered layout -> same coalesced pattern
//        as LDS). No Abuf, no staging, only 2 barriers per key (rowP
//        combine fence). Waves free-run and de-phase.
//      - ks=0 MFMA uses a zero C operand (no 48-reg acc zero-init)
//      - packed-f16 DPP quad reduce + pk_mul epilogue (R11, proven)
//      - __launch_bounds__(256,2): HARD 128-VGPR cap -> 4 waves/SIMD.
//    LDS 12,544 B (rowP only).
// ---------------------------------------------------------------------------
__launch_bounds__(256, 2)
__global__ void score_kernel(const __bf16* __restrict__ kfragA,
                             const __bf16* __restrict__ qfrag16,
                             const float* __restrict__ sig32,
                             const float* __restrict__ bn1g,
                             const float* __restrict__ bn1b,
                             __bf16* __restrict__ Sred)
{
    __shared__ unsigned rowP[2][16][98];   // 12,544 B: f16x2 row-pair partials

    int tid = threadIdx.x;
    int q0 = (blockIdx.x & 31) * 2;
    int kbase = (blockIdx.x >> 5) << 2;    // 32 k-groups of 4 keys
    int w = tid >> 6, lane = tid & 63, quad = lane >> 4, l16 = lane & 15;
    const float g1c = bn1g[0] * rsqrtf(1.f + 1e-5f);
    const float b1v = bn1b[0];
    // per-thread sig base: offset ((stile*12+3w)*64+lane)*4 floats
    //   = stile*3072 + (768*w + 4*lane)
    const float* sigb = sig32 + 768 * w + 4 * lane;

    // Hoist B (query) fragments for both q: 2 x 12 x 4 frags
    bf16x8 Bf[2][3][4];
#pragma unroll
    for (int p = 0; p < 2; ++p) {
        const __bf16* qb = qfrag16 + (size_t)(q0 + p) * 24576 + lane * 8;
#pragma unroll
        for (int j = 0; j < 3; ++j)
#pragma unroll
            for (int ks = 0; ks < 4; ++ks)
                Bf[p][j][ks] = *reinterpret_cast<const bf16x8*>(
                    qb + ((3 * w + j) * 4 + ks) * 512);
    }

#pragma unroll 1
    for (int kk = 0; kk < 4; ++kk) {
        int kidx = kbase + kk;
        // per-lane A base for this key: fragment layout is
        //   kp + stile*2048 + ks*512 + lane*8
        const __bf16* ka = kfragA + (size_t)kidx * 24576 + lane * 8;
        float cm[2][3];
#pragma unroll
        for (int p = 0; p < 2; ++p)
#pragma unroll
            for (int j = 0; j < 3; ++j) cm[p][j] = -3.0e38f;

#pragma unroll 1
        for (int sc = 0; sc < 6; ++sc) {      // 6 chunks of 32 s-rows
            f32x4 acc[2][2][3];               // [q][i][j]

#pragma unroll
            for (int ks = 0; ks < 4; ++ks) {
                bf16x8 a0 = *reinterpret_cast<const bf16x8*>(
                    ka + (sc * 2 + 0) * 2048 + ks * 512);
                bf16x8 a1 = *reinterpret_cast<const bf16x8*>(
                    ka + (sc * 2 + 1) * 2048 + ks * 512);
                if (ks == 0) {
                    const f32x4 Z4 = (f32x4){0.f, 0.f, 0.f, 0.f};
#pragma unroll
                    for (int j = 0; j < 3; ++j) {
                        acc[0][0][j] = MFMA16(a0, Bf[0][j][0], Z4);
                        acc[0][1][j] = MFMA16(a1, Bf[0][j][0], Z4);
                        acc[1][0][j] = MFMA16(a0, Bf[1][j][0], Z4);
                        acc[1][1][j] = MFMA16(a1, Bf[1][j][0], Z4);
                    }
                } else {
#pragma unroll
                    for (int j = 0; j < 3; ++j) {
                        acc[0][0][j] = MFMA16(a0, Bf[0][j][ks], acc[0][0][j]);
                        acc[0][1][j] = MFMA16(a1, Bf[0][j][ks], acc[0][1][j]);
                        acc[1][0][j] = MFMA16(a0, Bf[1][j][ks], acc[1][0][j]);
                        acc[1][1][j] = MFMA16(a1, Bf[1][j][ks], acc[1][1][j]);
                    }
                }
            }

            // epilogue: v = acc * sig (vector mul -> v_pk_mul_f32)
            //   s = 32*sc + 16i + quad*4 + r,  t = (3w+j)*16 + l16
#pragma unroll
            for (int i = 0; i < 2; ++i) {
                int stile = sc * 2 + i;
                const float* sp = sigb + stile * 3072;
                f32x4 s0 = *reinterpret_cast<const f32x4*>(sp);
                f32x4 s1 = *reinterpret_cast<const f32x4*>(sp + 256);
                f32x4 s2 = *reinterpret_cast<const f32x4*>(sp + 512);
#pragma unroll
                for (int p = 0; p < 2; ++p) {
                    f32x4 v0 = acc[p][i][0] * s0;
                    f32x4 v1 = acc[p][i][1] * s1;
                    f32x4 v2 = acc[p][i][2] * s2;
                    // col maxes over r folded into running cm (v_max3)
                    cm[p][0] = fmaxf(fmaxf(cm[p][0], fmaxf(v0[0], v0[1])),
                                     fmaxf(v0[2], v0[3]));
                    cm[p][1] = fmaxf(fmaxf(cm[p][1], fmaxf(v1[0], v1[1])),
                                     fmaxf(v1[2], v1[3]));
                    cm[p][2] = fmaxf(fmaxf(cm[p][2], fmaxf(v2[0], v2[1])),
                                     fmaxf(v2[2], v2[3]));
                    // row maxes over j (v_max3), pack row-pairs to f16
                    // (RTZ is monotone: max of rtz == rtz of max)
                    unsigned h01 = pkrtz_u(
                        fmaxf(fmaxf(v0[0], v1[0]), v2[0]),
                        fmaxf(fmaxf(v0[1], v1[1]), v2[1]));
                    unsigned h23 = pkrtz_u(
                        fmaxf(fmaxf(v0[2], v1[2]), v2[2]),
                        fmaxf(fmaxf(v0[3], v1[3]), v2[3]));
                    // quad reduce over l16 bits 0,1: DPP + v_pk_max_f16
                    // 0xB1 = quad_perm [1,0,3,2] (xor1),
                    // 0x4E = quad_perm [2,3,0,1] (xor2)
                    h01 = hmax2u(h01, dppu<0xB1>(h01));
                    h01 = hmax2u(h01, dppu<0x4E>(h01));
                    h23 = hmax2u(h23, dppu<0xB1>(h23));
                    h23 = hmax2u(h23, dppu<0x4E>(h23));
                    if ((l16 & 3) == 0) {
                        int rp = stile * 8 + quad * 2;
                        rowP[p][(l16 >> 2) * 4 + w][rp]     = h01;
                        rowP[p][(l16 >> 2) * 4 + w][rp + 1] = h23;
                    }
                }
            }
        }

        // col-max (max over s, indexed by t): reduce over quad, direct write
        // (no rowP dependence -> before the combine fence)
#pragma unroll
        for (int p = 0; p < 2; ++p) {
            size_t ob = (size_t)((q0 + p) * 128 + kidx) * 384;
            float v0 = cm[p][0], v1 = cm[p][1], v2 = cm[p][2];
            v0 = fmaxf(v0, __shfl_xor(v0, 16, 64));
            v0 = fmaxf(v0, __shfl_xor(v0, 32, 64));
            v1 = fmaxf(v1, __shfl_xor(v1, 16, 64));
            v1 = fmaxf(v1, __shfl_xor(v1, 32, 64));
            v2 = fmaxf(v2, __shfl_xor(v2, 16, 64));
            v2 = fmaxf(v2, __shfl_xor(v2, 32, 64));
            if (quad == 0) {
                Sred[ob + (3 * w + 0) * 16 + l16] = (__bf16)(v0 * g1c + b1v);
                Sred[ob + (3 * w + 1) * 16 + l16] = (__bf16)(v1 * g1c + b1v);
                Sred[ob + (3 * w + 2) * 16 + l16] = (__bf16)(v2 * g1c + b1v);
            }
        }

        __syncthreads();   // all waves' rowP writes for this key visible

        // row-max combine (max over t, indexed by s) for both q
        if (tid < 96) {
#pragma unroll
            for (int p = 0; p < 2; ++p) {
                size_t ob = (size_t)((q0 + p) * 128 + kidx) * 384;
                unsigned m = rowP[p][0][tid];
#pragma unroll
                for (int c = 1; c < 16; ++c)
                    m = hmax2u(m, rowP[p][c][tid]);
                __half2 hm = __builtin_bit_cast(__half2, m);
                float lo = __low2float(hm), hi = __high2float(hm);
                unsigned two =
                    (unsigned)__builtin_bit_cast(unsigned short,
                        (__bf16)(lo * g1c + b1v)) |
                    ((unsigned)__builtin_bit_cast(unsigned short,
                        (__bf16)(hi * g1c + b1v)) << 16);
                *reinterpret_cast<unsigned*>(&Sred[ob + 192 + 2 * tid]) = two;
            }
        }

        __syncthreads();   // combine done before next key's rowP writes
    }
}

// ---------------------------------------------------------------------------
// Kernel 3: fused fc2 + bn2 + relu + fc3 + pair-sum + bn3 (unchanged).
// ---------------------------------------------------------------------------
__launch_bounds__(512, 1)
__global__ void mlp_kernel(const __bf16* __restrict__ Sred,
                           const __bf16* __restrict__ fc2w_bf,
                           const float* __restrict__ h2,
                           const float* __restrict__ bb2,
                           const float* __restrict__ f3,
                           const float* __restrict__ fc3b,
                           const float* __restrict__ bn3g,
                           const float* __restrict__ bn3b,
                           float* __restrict__ out)
{
    __shared__ __bf16 As[64][200];
    __shared__ float  psum_lds[8][64];
    int bx = blockIdx.x, tid = threadIdx.x;
    const __bf16* asrc = Sred + (size_t)bx * (64 * 192);
#pragma unroll
    for (int it = 0; it < 3; ++it) {
        int e = (it * 512 + tid) * 8;
        int r = e / 192, c = e - r * 192;
        *reinterpret_cast<bf16x8*>(&As[r][c]) =
            *reinterpret_cast<const bf16x8*>(asrc + e);
    }
    __syncthreads();

    int wv = tid >> 6, lane = tid & 63, quad = lane >> 4, l16 = lane & 15;
    bf16x8 af[4][6];
#pragma unroll
    for (int m = 0; m < 4; ++m)
#pragma unroll
        for (int kk = 0; kk < 6; ++kk)
            af[m][kk] = *reinterpret_cast<const bf16x8*>(
                &As[m * 16 + l16][kk * 32 + quad * 8]);

    float ps[4][4] = {{0.f,0.f,0.f,0.f},{0.f,0.f,0.f,0.f},
                      {0.f,0.f,0.f,0.f},{0.f,0.f,0.f,0.f}};
    for (int nt = 0; nt < 16; ++nt) {
        int n0 = wv * 256 + nt * 16;
        f32x4 acc[4];
#pragma unroll
        for (int m = 0; m < 4; ++m) acc[m] = (f32x4){0.f, 0.f, 0.f, 0.f};
        const __bf16* bp = fc2w_bf + (size_t)(n0 + l16) * 192 + quad * 8;
#pragma unroll
        for (int kk = 0; kk < 6; ++kk) {
            bf16x8 b = *reinterpret_cast<const bf16x8*>(bp + kk * 32);
#pragma unroll
            for (int m = 0; m < 4; ++m) acc[m] = MFMA16(af[m][kk], b, acc[m]);
        }
        int n = n0 + l16;
        float hh = h2[n], bb = bb2[n], ffv = f3[n];
#pragma unroll
        for (int m = 0; m < 4; ++m)
#pragma unroll
            for (int r = 0; r < 4; ++r)
                ps[m][r] += fmaxf(acc[m][r] * hh + bb, 0.f) * ffv;
    }
#pragma unroll
    for (int m = 0; m < 4; ++m)
#pragma unroll
        for (int r = 0; r < 4; ++r) {
            float v = ps[m][r];
            v += __shfl_xor(v, 1, 64);
            v += __shfl_xor(v, 2, 64);
            v += __shfl_xor(v, 4, 64);
            v += __shfl_xor(v, 8, 64);
            if (l16 == 0) psum_lds[wv][m * 16 + quad * 4 + r] = v;
        }
    __syncthreads();
    if (tid < 32) {
        float s = 0.f;
#pragma unroll
        for (int w = 0; w < 8; ++w)
            s += psum_lds[w][2 * tid] + psum_lds[w][2 * tid + 1];
        const float c1 = rsqrtf(1.f + 1e-5f);
        out[bx * 32 + tid] = (s + 2.f * fc3b[0]) * (bn3g[0] * c1) + bn3b[0];
    }
}

// ---------------------------------------------------------------------------
extern "C" void kernel_launch(void* const* d_in, const int* in_sizes, int n_in,
                              void* d_out, int out_size, void* d_ws, size_t ws_size,
                              hipStream_t stream)
{
    const float* q_feat = (const float*)d_in[0];
    const float* g_feat = (const float*)d_in[1];
    const float* se     = (const float*)d_in[2];
    const float* fc0w   = (const float*)d_in[3];
    const float* fc0b   = (const float*)d_in[4];
    const float* fc2w   = (const float*)d_in[5];
    const float* fc2b   = (const float*)d_in[6];
    const float* fc3w   = (const float*)d_in[7];
    const float* fc3b   = (const float*)d_in[8];
    const float* bn1g   = (const float*)d_in[9];
    const float* bn1b   = (const float*)d_in[10];
    const float* bn2g   = (const float*)d_in[11];
    const float* bn2b   = (const float*)d_in[12];
    const float* bn3g   = (const float*)d_in[13];
    const float* bn3b   = (const float*)d_in[14];
    float* out = (float*)d_out;

    char* ws = (char*)d_ws;
    __bf16* kfragA   = (__bf16*)(ws);                 //  6,291,456 B
    __bf16* qfrag16  = (__bf16*)(ws +  6291456);      //  3,145,728 B
    float*  sig32    = (float*) (ws +  9437184);      //    147,456 B
    __bf16* fc2w_bf  = (__bf16*)(ws +  9584640);      //    786,432 B
    float*  h2       = (float*) (ws + 10371072);      //      8,192 B
    float*  bb2      = (float*) (ws + 10379264);      //      8,192 B
    float*  f3       = (float*) (ws + 10387456);      //      8,192 B
    __bf16* Sred     = (__bf16*)(ws + 10395648);      //  6,291,456 B (16.69 MB total)

    proj_prep_kernel<<<1312, 256, 0, stream>>>(q_feat, g_feat, fc0w, fc0b, se,
                                               fc2w, fc2b, bn2g, bn2b, fc3w,
                                               kfragA, qfrag16, sig32, fc2w_bf,
                                               h2, bb2, f3);
    score_kernel<<<1024, 256, 0, stream>>>(kfragA, qfrag16, sig32, bn1g, bn1b, Sred);
    mlp_kernel<<<256, 512, 0, stream>>>(Sred, fc2w_bf, h2, bb2, f3,
                                        fc3b, bn3g, bn3b, out);
}